// Round 1
// baseline (847.638 us; speedup 1.0000x reference)
//
#include <hip/hip_runtime.h>
#include <math.h>

// ExpressiveUpdateRule: out[b,o,i] = W[b,o,i] - scale_b * (W[b,o,:]·x_b - g[b,o]) * x_b[i]
// scale_b = 1 / (LAMBDA_SQ + softplus(x_b·eta_w + eta_b))
// B=128, D=1024, fp32. Memory-bound: 512 MiB read (W once) + 512 MiB write.

constexpr int D = 1024;
constexpr float LAMBDA_SQ = 1024.0f;
constexpr int ROWS_PER_BLOCK = 16;           // 4 waves x 4 rows each
constexpr int BLOCKS_PER_BATCH = D / ROWS_PER_BLOCK;  // 64

// --- kernel 1: scale[b] = 1/(LAMBDA_SQ + softplus(x_b . eta_w + eta_b)) ---
__global__ __launch_bounds__(256) void scale_kernel(const float* __restrict__ x,
                                                    const float* __restrict__ eta_w,
                                                    const float* __restrict__ eta_b,
                                                    float* __restrict__ scale_out) {
    const int b = blockIdx.x;
    const int tid = threadIdx.x;
    const float4 xf = ((const float4*)(x + (size_t)b * D))[tid];
    const float4 wf = ((const float4*)eta_w)[tid];
    float p = xf.x * wf.x + xf.y * wf.y + xf.z * wf.z + xf.w * wf.w;
    #pragma unroll
    for (int off = 32; off > 0; off >>= 1) p += __shfl_xor(p, off);
    __shared__ float red[4];
    if ((tid & 63) == 0) red[tid >> 6] = p;
    __syncthreads();
    if (tid == 0) {
        float z = red[0] + red[1] + red[2] + red[3] + eta_b[0];
        // numerically-stable softplus
        float sp = fmaxf(z, 0.0f) + log1pf(expf(-fabsf(z)));
        scale_out[b] = 1.0f / (LAMBDA_SQ + sp);
    }
}

// --- kernel 2: fused matvec + rank-1 update. One wave per row; W row lives
// in 16 regs/lane for both the dot and the rewrite (W read exactly once). ---
__global__ __launch_bounds__(256) void update_kernel(const float* __restrict__ W,
                                                     const float* __restrict__ x,
                                                     const float* __restrict__ g,
                                                     const float* __restrict__ scale,
                                                     float* __restrict__ out) {
    __shared__ float xs[D];
    const int tid = threadIdx.x;
    const int b = blockIdx.x / BLOCKS_PER_BATCH;
    const int row0 = (blockIdx.x % BLOCKS_PER_BATCH) * ROWS_PER_BLOCK;

    // stage x[b,:] into LDS (4 KiB), coalesced float4
    ((float4*)xs)[tid] = ((const float4*)(x + (size_t)b * D))[tid];
    __syncthreads();

    const float s = scale[b];
    const int wave = tid >> 6;
    const int lane = tid & 63;

    #pragma unroll
    for (int r = 0; r < ROWS_PER_BLOCK / 4; ++r) {
        const int row = row0 + r * 4 + wave;
        const size_t row_base = ((size_t)b * D + row) * D;
        const float4* __restrict__ wrow = (const float4*)(W + row_base);
        float4* __restrict__ orow = (float4*)(out + row_base);

        float4 wreg[4], xreg[4];
        // 4 chunks: chunk c covers float4 indices [c*64 .. c*64+63], lane-coalesced
        #pragma unroll
        for (int c = 0; c < 4; ++c) {
            const int idx = c * 64 + lane;
            wreg[c] = wrow[idx];
            xreg[c] = ((const float4*)xs)[idx];
        }
        float dot = 0.0f;
        #pragma unroll
        for (int c = 0; c < 4; ++c) {
            dot += wreg[c].x * xreg[c].x + wreg[c].y * xreg[c].y
                 + wreg[c].z * xreg[c].z + wreg[c].w * xreg[c].w;
        }
        // 64-lane butterfly reduce: all lanes end with full row dot
        #pragma unroll
        for (int off = 32; off > 0; off >>= 1) dot += __shfl_xor(dot, off);

        const float err = dot - g[(size_t)b * D + row];  // broadcast load, same addr
        const float f = s * err;
        #pragma unroll
        for (int c = 0; c < 4; ++c) {
            const int idx = c * 64 + lane;
            float4 o;
            o.x = wreg[c].x - f * xreg[c].x;
            o.y = wreg[c].y - f * xreg[c].y;
            o.z = wreg[c].z - f * xreg[c].z;
            o.w = wreg[c].w - f * xreg[c].w;
            orow[idx] = o;
        }
    }
}

extern "C" void kernel_launch(void* const* d_in, const int* in_sizes, int n_in,
                              void* d_out, int out_size, void* d_ws, size_t ws_size,
                              hipStream_t stream) {
    const float* W     = (const float*)d_in[0];
    const float* x     = (const float*)d_in[1];
    const float* g     = (const float*)d_in[2];
    const float* eta_w = (const float*)d_in[3];
    const float* eta_b = (const float*)d_in[4];
    float* out   = (float*)d_out;
    float* scale = (float*)d_ws;  // 128 floats

    const int B = in_sizes[1] / D;  // 128
    scale_kernel<<<B, 256, 0, stream>>>(x, eta_w, eta_b, scale);
    update_kernel<<<B * BLOCKS_PER_BATCH, 256, 0, stream>>>(W, x, g, scale, out);
}